// Round 1
// baseline (410.649 us; speedup 1.0000x reference)
//
#include <hip/hip_runtime.h>
#include <cstdint>
#include <cstddef>

#define FP8_MAXV 448.0f
#define AMAX_EPS 1e-8f
#define MOMENTUM 0.95f

// Problem constants: x[8192,4096] f32, w[4096,4096] f32, bias[4096] f32
#define M_DIM 8192
#define N_DIM 4096
#define K_DIM 4096

#define XBLOCKS 2048
#define WBLOCKS 1024

// E8M0 scale = 127 -> 2^0 = 1.0 in every byte (opsel-proof)
#define SCALE_ONE 0x7F7F7F7F

typedef float f32x4 __attribute__((ext_vector_type(4)));
typedef int   i32x4 __attribute__((ext_vector_type(4)));
typedef int   i32x8 __attribute__((ext_vector_type(8)));

// ---------------------------------------------------------------------------
// async global -> LDS, 16B per lane. HW writes lds_base + lane*16.
// ---------------------------------------------------------------------------
__device__ __forceinline__ void gload_lds16(const void* g, void* l) {
  __builtin_amdgcn_global_load_lds(
      (const __attribute__((address_space(1))) void*)g,
      (__attribute__((address_space(3))) void*)l, 16, 0, 0);
}

// ---------------------------------------------------------------------------
// Fused quantize (UNCHANGED for clean attribution): blocks [0,2048) handle x,
// [2048,3072) handle w. fp32 -> fp8 e4m3, fused per-block |max| partials.
// ---------------------------------------------------------------------------
__global__ __launch_bounds__(256) void k_quant(
    const float* __restrict__ x, const float* __restrict__ w,
    unsigned int* __restrict__ xq, unsigned int* __restrict__ wq,
    const float* __restrict__ ax_buf, const float* __restrict__ aw_buf,
    float* __restrict__ xpart, float* __restrict__ wpart) {
  const float* in;
  unsigned int* outq;
  float* part;
  int bid, nblocks, n4;
  float sc;
  if (blockIdx.x < XBLOCKS) {
    in = x; outq = xq; part = xpart;
    bid = blockIdx.x; nblocks = XBLOCKS; n4 = (M_DIM * K_DIM) / 4;
    sc = FP8_MAXV / fmaxf(ax_buf[0], AMAX_EPS);
  } else {
    in = w; outq = wq; part = wpart;
    bid = blockIdx.x - XBLOCKS; nblocks = WBLOCKS; n4 = (N_DIM * K_DIM) / 4;
    sc = FP8_MAXV / fmaxf(aw_buf[0], AMAX_EPS);
  }
  float lm = 0.0f;
  const int stride = nblocks * 256;
  for (int i = bid * 256 + threadIdx.x; i < n4; i += stride) {
    float4 v = ((const float4*)in)[i];
    lm = fmaxf(lm, fmaxf(fmaxf(fabsf(v.x), fabsf(v.y)),
                         fmaxf(fabsf(v.z), fabsf(v.w))));
    float a0 = fminf(fmaxf(v.x * sc, -FP8_MAXV), FP8_MAXV);
    float a1 = fminf(fmaxf(v.y * sc, -FP8_MAXV), FP8_MAXV);
    float a2 = fminf(fmaxf(v.z * sc, -FP8_MAXV), FP8_MAXV);
    float a3 = fminf(fmaxf(v.w * sc, -FP8_MAXV), FP8_MAXV);
    int p = 0;
    p = __builtin_amdgcn_cvt_pk_fp8_f32(a0, a1, p, false);  // bytes 0,1
    p = __builtin_amdgcn_cvt_pk_fp8_f32(a2, a3, p, true);   // bytes 2,3
    outq[i] = (unsigned int)p;
  }
  #pragma unroll
  for (int off = 32; off > 0; off >>= 1)
    lm = fmaxf(lm, __shfl_down(lm, off));
  __shared__ float smax[4];
  if ((threadIdx.x & 63) == 0) smax[threadIdx.x >> 6] = lm;
  __syncthreads();
  if (threadIdx.x == 0)
    part[bid] = fmaxf(fmaxf(smax[0], smax[1]), fmaxf(smax[2], smax[3]));
}

// ---------------------------------------------------------------------------
// FP8 GEMM, 256x256 tile, BK=128 bytes, 512 threads = 8 waves (2M x 4N).
// Double-buffered LDS (2 x 64KB), 4-phase schedule per K-tile with raw
// s_barrier (NO vmcnt drain at phase barriers), counted-vmcnt discipline:
// DMAs for tile t+1 are issued in seg0 of tile t and only waited at the end
// of seg2 (~2 phases ~1100 cyc later), so they stay in flight across 3
// barriers. s_setprio(1) wraps each 8-MFMA cluster. Every MFMA cluster
// consumes LDS reads issued before the PREVIOUS barrier (latency hidden).
//
// LDS swizzle (verified in prior rounds): 16B group g of row r stored at
// phys group g ^ (r&7). Staging pre-swizzles the per-lane GLOBAL source so
// the linear gload_lds write lands swizzled; reads XOR the group with m&7.
// ---------------------------------------------------------------------------
__global__ __launch_bounds__(512, 2) void k_gemm(
    const unsigned char* __restrict__ Aq, const unsigned char* __restrict__ Bq,
    const float* __restrict__ bias,
    const float* __restrict__ ax_buf, const float* __restrict__ aw_buf,
    const float* __restrict__ xpart, const float* __restrict__ wpart,
    float* __restrict__ out) {
  __shared__ __align__(16) unsigned char ldsA[2][256 * 128];  // 64 KB
  __shared__ __align__(16) unsigned char ldsB[2][256 * 128];  // 64 KB

  const int tid = threadIdx.x;
  const int w = tid >> 6;         // wave 0..7
  const int l = tid & 63;         // lane
  const int m = l & 15;           // fragment row/col within 16
  const int q = l >> 4;           // quad 0..3
  const int mk = m & 7;           // read-side swizzle term
  const int wr = (w >> 2) * 128;  // wave M offset: 0 or 128
  const int wc = (w & 3) * 64;    // wave N offset: 0,64,128,192
  const int blockRow = blockIdx.y * 256;
  const int blockCol = blockIdx.x * 256;

  // per-thread constant swizzled byte offsets for the lo/hi 16B of a frag
  const int xlo = ((2 * q) ^ mk) * 16;
  const int xhi = ((2 * q + 1) ^ mk) * 16;

  // staging: wave w stages rows [w*32, w*32+32) in 4 slots of 8 rows.
  // lane l -> row (l>>3) of slot, sources swizzled group (l&7)^(l>>3).
  const int srow = l >> 3;
  const int sgrp = ((l & 7) ^ srow) * 16;
  const unsigned char* gA = Aq + (size_t)(blockRow + w * 32 + srow) * K_DIM + sgrp;
  const unsigned char* gB = Bq + (size_t)(blockCol + w * 32 + srow) * K_DIM + sgrp;

#define STAGE(bufidx, k0)                                              \
  { _Pragma("unroll") for (int s = 0; s < 4; ++s) {                    \
      gload_lds16(gA + (k0) + (size_t)(s * 8) * K_DIM,                 \
                  &ldsA[bufidx][w * 4096 + s * 1024]);                 \
      gload_lds16(gB + (k0) + (size_t)(s * 8) * K_DIM,                 \
                  &ldsB[bufidx][w * 4096 + s * 1024]);                 \
  } }

#define FRAG2(lo, hi, off)                                             \
  __builtin_shufflevector(*(const i32x4*)((lo) + (off)),               \
                          *(const i32x4*)((hi) + (off)), 0, 1, 2, 3, 4, 5, 6, 7)

#define MFMA_PAIR(i0, aX, aY)                                          \
  { __builtin_amdgcn_s_setprio(1);                                     \
    _Pragma("unroll") for (int j = 0; j < 4; ++j) {                    \
      acc[(i0)][j] = __builtin_amdgcn_mfma_scale_f32_16x16x128_f8f6f4( \
          aX, b[j], acc[(i0)][j], 0, 0, 0, SCALE_ONE, 0, SCALE_ONE);   \
      acc[(i0) + 1][j] = __builtin_amdgcn_mfma_scale_f32_16x16x128_f8f6f4( \
          aY, b[j], acc[(i0) + 1][j], 0, 0, 0, SCALE_ONE, 0, SCALE_ONE);   \
    }                                                                  \
    __builtin_amdgcn_s_setprio(0); }

  f32x4 acc[8][4] = {};
  const int NT = K_DIM / 128;  // 32 K-tiles

  // prologue: stage tile 0, wait, preload b / a0 / a1 from buf0
  STAGE(0, 0);
  asm volatile("s_waitcnt vmcnt(0)" ::: "memory");
  __builtin_amdgcn_s_barrier();

  i32x8 b[4], a0f, a1f;
  {
    const unsigned char* Blo = &ldsB[0][(wc + m) * 128 + xlo];
    const unsigned char* Bhi = &ldsB[0][(wc + m) * 128 + xhi];
    const unsigned char* Alo = &ldsA[0][(wr + m) * 128 + xlo];
    const unsigned char* Ahi = &ldsA[0][(wr + m) * 128 + xhi];
    #pragma unroll
    for (int j = 0; j < 4; ++j) b[j] = FRAG2(Blo, Bhi, j * 2048);
    a0f = FRAG2(Alo, Ahi, 0);
    a1f = FRAG2(Alo, Ahi, 2048);
  }

  for (int kt = 0; kt < NT; ++kt) {
    const int cur = kt & 1;
    const unsigned char* Alo = &ldsA[cur][(wr + m) * 128 + xlo];
    const unsigned char* Ahi = &ldsA[cur][(wr + m) * 128 + xhi];

    // ---- seg0: issue next-tile DMA early; MFMA i=0,1; read a2,a3 ----
    if (kt + 1 < NT) STAGE(cur ^ 1, (kt + 1) * 128);
    MFMA_PAIR(0, a0f, a1f);
    i32x8 a2f = FRAG2(Alo, Ahi, 2 * 2048);
    i32x8 a3f = FRAG2(Alo, Ahi, 3 * 2048);
    __builtin_amdgcn_s_barrier();

    // ---- seg1: MFMA i=2,3; read a4,a5 ----
    MFMA_PAIR(2, a2f, a3f);
    i32x8 a4f = FRAG2(Alo, Ahi, 4 * 2048);
    i32x8 a5f = FRAG2(Alo, Ahi, 5 * 2048);
    __builtin_amdgcn_s_barrier();

    // ---- seg2: MFMA i=4,5; read a6,a7; counted wait for next-tile DMA ----
    MFMA_PAIR(4, a4f, a5f);
    i32x8 a6f = FRAG2(Alo, Ahi, 6 * 2048);
    i32x8 a7f = FRAG2(Alo, Ahi, 7 * 2048);
    asm volatile("s_waitcnt vmcnt(0)" ::: "memory");  // DMAs ~2 phases old
    __builtin_amdgcn_s_barrier();

    // ---- seg3: MFMA i=6,7; preload next tile's b / a0 / a1 ----
    MFMA_PAIR(6, a6f, a7f);
    if (kt + 1 < NT) {
      const int nxt = cur ^ 1;
      const unsigned char* Bnlo = &ldsB[nxt][(wc + m) * 128 + xlo];
      const unsigned char* Bnhi = &ldsB[nxt][(wc + m) * 128 + xhi];
      const unsigned char* Anlo = &ldsA[nxt][(wr + m) * 128 + xlo];
      const unsigned char* Anhi = &ldsA[nxt][(wr + m) * 128 + xhi];
      #pragma unroll
      for (int j = 0; j < 4; ++j) b[j] = FRAG2(Bnlo, Bnhi, j * 2048);
      a0f = FRAG2(Anlo, Anhi, 0);
      a1f = FRAG2(Anlo, Anhi, 2048);
    }
    __builtin_amdgcn_s_barrier();
  }

  // dequant: out = acc * clip(ax)*clip(aw)/448^2 + bias
  const float inv = fmaxf(ax_buf[0], AMAX_EPS) * fmaxf(aw_buf[0], AMAX_EPS) *
                    (1.0f / (FP8_MAXV * FP8_MAXV));

  // C/D layout (verified): col = lane&15, row = (lane>>4)*4 + reg
  #pragma unroll
  for (int j = 0; j < 4; ++j) {
    const int colg = blockCol + wc + j * 16 + m;
    const float bv = bias[colg];
    #pragma unroll
    for (int i = 0; i < 8; ++i) {
      const int rowg = blockRow + wr + i * 16 + q * 4;
      #pragma unroll
      for (int r = 0; r < 4; ++r)
        out[(size_t)(rowg + r) * N_DIM + colg] = acc[i][j][r] * inv + bv;
    }
  }

  // ---- amax EMA finalize (block (0,0) only) ----
  if (blockIdx.x == 0 && blockIdx.y == 0) {
    float mx = 0.0f, mw = 0.0f;
    for (int i = tid; i < XBLOCKS; i += 512) mx = fmaxf(mx, xpart[i]);
    for (int i = tid; i < WBLOCKS; i += 512) mw = fmaxf(mw, wpart[i]);
    #pragma unroll
    for (int off = 32; off > 0; off >>= 1) {
      mx = fmaxf(mx, __shfl_down(mx, off));
      mw = fmaxf(mw, __shfl_down(mw, off));
    }
    __syncthreads();  // all MFMA LDS reads done; safe to reuse ldsA
    float* red = (float*)ldsA;
    if (l == 0) { red[w] = mx; red[8 + w] = mw; }
    __syncthreads();
    if (tid == 0) {
      mx = red[0]; mw = red[8];
      #pragma unroll
      for (int i = 1; i < 8; ++i) {
        mx = fmaxf(mx, red[i]);
        mw = fmaxf(mw, red[8 + i]);
      }
      float* tail = out + (size_t)M_DIM * N_DIM;
      tail[0] = fmaxf(fmaxf(ax_buf[0] * MOMENTUM, mx), AMAX_EPS);
      tail[1] = fmaxf(fmaxf(aw_buf[0] * MOMENTUM, mw), AMAX_EPS);
    }
  }
}

// ---------------------------------------------------------------------------
extern "C" void kernel_launch(void* const* d_in, const int* in_sizes, int n_in,
                              void* d_out, int out_size, void* d_ws, size_t ws_size,
                              hipStream_t stream) {
  const float* x      = (const float*)d_in[0];  // [8192,4096]
  const float* weight = (const float*)d_in[1];  // [4096,4096]
  const float* bias   = (const float*)d_in[2];  // [4096]
  const float* in_ax  = (const float*)d_in[3];  // scalar
  const float* in_aw  = (const float*)d_in[4];  // scalar
  float* out = (float*)d_out;

  // workspace layout: partial maxes then fp8 buffers (16B-aligned regions)
  float* xpart = (float*)d_ws;                       // 2048 floats
  float* wpart = xpart + XBLOCKS;                    // 1024 floats
  unsigned char* xq = (unsigned char*)d_ws + 16384;  // M*K fp8
  unsigned char* wq = xq + (size_t)M_DIM * K_DIM;    // N*K fp8

  k_quant<<<XBLOCKS + WBLOCKS, 256, 0, stream>>>(
      x, weight, (unsigned int*)xq, (unsigned int*)wq, in_ax, in_aw,
      xpart, wpart);

  dim3 grid(N_DIM / 256, M_DIM / 256);  // 16 x 32 = 512 blocks
  k_gemm<<<grid, 512, 0, stream>>>(xq, wq, bias, in_ax, in_aw,
                                   xpart, wpart, out);
}